// Round 11
// baseline (399.429 us; speedup 1.0000x reference)
//
#include <hip/hip_runtime.h>
#include <hip/hip_bf16.h>
#include <math.h>

#define NN 8192
#define KK 1000
#define SS 8
#define DD 1024
#define RR (KK * SS)   // 8000 memory rows
#define RRP 8192       // padded to 32 * 256

typedef float f32x4 __attribute__((ext_vector_type(4)));
typedef int i32x4 __attribute__((ext_vector_type(4)));
typedef int i32x8 __attribute__((ext_vector_type(8)));
typedef unsigned char u8;

// direct global->LDS DMA, 16 B per lane; LDS dest = wave-uniform base + lane*16
#define GLD16(gsrc, ldst)                                                     \
  __builtin_amdgcn_global_load_lds(                                           \
      (const __attribute__((address_space(1))) unsigned int*)(gsrc),          \
      (__attribute__((address_space(3))) unsigned int*)(ldst), 16, 0, 0)

#define SBAR() asm volatile("s_barrier" ::: "memory")
#define WAITVM(n) asm volatile("s_waitcnt vmcnt(" #n ")" ::: "memory")

// ---------------------------------------------------------------------------
// Kernel A: per-sample softmax stats -> packed candidate record.
// ---------------------------------------------------------------------------
__global__ __launch_bounds__(256) void stats_kernel(
    const float* __restrict__ tl, int2* __restrict__ cand) {
  __shared__ float sv[KK];
  __shared__ float redv[256];
  __shared__ int   redi[256];
  const int n = blockIdx.x;
  const int t = threadIdx.x;
  const float* row = tl + (size_t)n * KK;
  for (int j = t; j < KK; j += 256) sv[j] = row[j];
  __syncthreads();

  float bv = -INFINITY; int bi = KK;
  for (int j = t; j < KK; j += 256) { float v = sv[j]; if (v > bv) { bv = v; bi = j; } }
  redv[t] = bv; redi[t] = bi;
  __syncthreads();
  for (int off = 128; off > 0; off >>= 1) {
    if (t < off) {
      float ov = redv[t + off]; int oi = redi[t + off];
      if (ov > redv[t] || (ov == redv[t] && oi < redi[t])) { redv[t] = ov; redi[t] = oi; }
    }
    __syncthreads();
  }
  const float m = redv[0];
  const int lab = redi[0];
  __syncthreads();

  float z = 0.f;
  for (int j = t; j < KK; j += 256) z += expf(sv[j] - m);
  redv[t] = z;
  __syncthreads();
  for (int off = 128; off > 0; off >>= 1) {
    if (t < off) redv[t] += redv[t + off];
    __syncthreads();
  }
  const float Z = redv[0];
  __syncthreads();

  float h = 0.f;
  for (int j = t; j < KK; j += 256) {
    float p = expf(sv[j] - m) / Z;
    h -= p * logf(p + 1e-6f);
  }
  redv[t] = h;
  __syncthreads();
  for (int off = 128; off > 0; off >>= 1) {
    if (t < off) redv[t] += redv[t + off];
    __syncthreads();
  }
  if (t == 0) {
    const float H = redv[0];
    const float plab = 1.0f / Z;
    const bool c = (plab > 0.03f) && (H > 0.2f) && (H < 0.5f);
    cand[n] = make_int2(c ? lab : -1, __float_as_int(H));
  }
}

// ---------------------------------------------------------------------------
// Kernel B: per-class sequential eviction, wave-parallel scan.
// ---------------------------------------------------------------------------
__global__ __launch_bounds__(256) void select_kernel(
    const int2* __restrict__ cand, const float* __restrict__ ment,
    int* __restrict__ sel) {
  const int w = threadIdx.x >> 6;
  const int l = threadIdx.x & 63;
  const int k = blockIdx.x * 4 + w;
  if (k >= KK) return;

  float ent[SS]; int idx[SS];
  #pragma unroll
  for (int s = 0; s < SS; ++s) { ent[s] = ment[k * SS + s]; idx[s] = -1; }

  for (int base = 0; base < NN; base += 64) {
    const int2 c = cand[base + l];
    unsigned long long msk = __ballot(c.x == k);
    while (msk) {
      const int src = __ffsll((long long)msk) - 1;
      msk &= msk - 1;
      const float H = __shfl(__int_as_float(c.y), src);
      float mx = ent[0]; int mi = 0;
      #pragma unroll
      for (int s = 1; s < SS; ++s) if (ent[s] > mx) { mx = ent[s]; mi = s; }
      if (H < mx) { ent[mi] = H; idx[mi] = base + src; }
    }
  }
  if (l == 0) {
    #pragma unroll
    for (int s = 0; s < SS; ++s) sel[k * SS + s] = idx[s];
  }
}

// ---------------------------------------------------------------------------
// Kernel B2: fused convert+gather -> fp8 e4m3 (OCP) matrices.
// r < NN:  xq[r]  = fp8(x[r]);  r >= NN: Bq[r-NN] = fp8(final mem row) or 0.
// Inputs are N(0,1) (|v| << 448): direct conversion, no scaling needed.
// Identical pack order for A and B => any within-row byte permutation
// cancels in the dot product.
// ---------------------------------------------------------------------------
__global__ __launch_bounds__(128) void convgather_kernel(
    const float* __restrict__ x, const float* __restrict__ mem,
    const int* __restrict__ sel, u8* __restrict__ xq, u8* __restrict__ Bq) {
  const int r = blockIdx.x;
  const int t = threadIdx.x;
  const float* src;
  u8* dst;
  if (r < NN) {
    src = x + (size_t)r * DD;
    dst = xq + (size_t)r * DD;
  } else {
    const int rr = r - NN;
    dst = Bq + (size_t)rr * DD;
    if (rr >= RR) {
      *(int2*)(dst + t * 8) = make_int2(0, 0);
      return;
    }
    const int sl = sel[rr];
    src = (sl >= 0) ? (x + (size_t)sl * DD) : (mem + (size_t)rr * DD);
  }
  const float4 a = *(const float4*)(src + t * 8);
  const float4 b = *(const float4*)(src + t * 8 + 4);
  int lo = __builtin_amdgcn_cvt_pk_fp8_f32(a.x, a.y, 0, false);
  lo = __builtin_amdgcn_cvt_pk_fp8_f32(a.z, a.w, lo, true);
  int hi = __builtin_amdgcn_cvt_pk_fp8_f32(b.x, b.y, 0, false);
  hi = __builtin_amdgcn_cvt_pk_fp8_f32(b.z, b.w, hi, true);
  *(int2*)(dst + t * 8) = make_int2(lo, hi);
}

// ---------------------------------------------------------------------------
// Kernel C: MX-fp8 MFMA GEMM (scale=1) + exp-sum epilogue, 4-phase pipeline.
// BM=BN=256, BK=128 fp8, 8 waves (2M x 4N), 512 threads. 2 LDS buffers of
// (A 256x128B + B 256x128B) = 64 KB each; 128 KB total.
// mfma_scale_f32_16x16x128_f8f6f4, cbsz=blgp=0 (fp8/fp8), scales 0x7F7F7F7F
// (E8M0 127 = 2^0) -> exact fp8 dot at 2x bf16 rate; opsel-layout-proof
// since every scale byte is 127.
// A-frag: lane l: row=l&15, k=(l>>4)*32+j (32 contiguous fp8 = 2 b128 reads);
// B-frag: col=l&15, same k. C/D layout unchanged (shape-determined).
// K-loop: 8 steps; per step 4 phases x {ds_read subtile || 2xGLD16 stage ||
// SBAR || setprio 8 MFMA setprio || SBAR}. Stage pairs for step T+1:
//   ph0:(A-c0,A-c2) ph1:(B-c0,B-c2) ph2:(B-c1,B-c3) ph3:(A-c1,A-c3)
// vmcnt ledger (2 issues/phase, FIFO): boundary WAITVM(2) -> pairs 0,1,2 of
// T+1 landed (covers ph0/ph1 reads: B chunk wn in pairs 1,2; A chunk 2wm in
// pair 0); ph2 WAITVM(4) drains pair3 of T (A chunks 1,3 for mi4-7); tail
// WAITVM(0). WAR: stage buffer (T+1)&1 vs read buffer T&1 disjoint.
// Chunk-XOR swizzle (128B rows, 8 chunks, 0 conflicts r5-r10): LDS slot
// c^(row&7) holds global chunk c; staged via permuted per-lane global source,
// read with the same XOR.
// ---------------------------------------------------------------------------
#define BKQ 128
#define NTS (DD / BKQ)   // 8 K-steps
#define LDSB 65536       // bytes per buffer (A 32768 + B 32768)

__global__ __launch_bounds__(512, 2) void logits_kernel(
    const u8* __restrict__ xq, const u8* __restrict__ Bq,
    float* __restrict__ out) {
  __shared__ u8 lds[2 * LDSB];  // 128 KB
  const int t = threadIdx.x;
  const int w = t >> 6;    // wave 0..7
  const int l = t & 63;
  const int wm = w >> 2;   // 0..1: M-half (128 rows)
  const int wn = w & 3;    // 0..3: N-quarter (64 cols)
  const int n0 = blockIdx.x * 256;
  const int r0 = blockIdx.y * 256;

  // ---- staging constants: one GLD16 = 8 rows of 128 B per wave-call ----
  // lane covers row c*64 + w*8 + (l>>3); LDS slot chunk = l&7,
  // global chunk = (l&7) ^ (row&7) = (l&7) ^ ((l>>3)&7)
  const int srow = w * 8 + (l >> 3);
  const int gcolb = (((l & 7) ^ ((l >> 3) & 7)) << 4);  // bytes
  const u8* gA = xq + (size_t)(n0 + srow) * DD + gcolb;
  const u8* gB = Bq + (size_t)(r0 + srow) * DD + gcolb;

#define STAGE_AC(T, c)                                                        \
  GLD16(gA + (size_t)(c) * 64 * DD + (size_t)(T) * BKQ,                       \
        lds + ((T) & 1) * LDSB + (c) * 8192 + w * 1024)
#define STAGE_BC(T, c)                                                        \
  GLD16(gB + (size_t)(c) * 64 * DD + (size_t)(T) * BKQ,                       \
        lds + ((T) & 1) * LDSB + 32768 + (c) * 8192 + w * 1024)

  // ---- read-side constants (bytes) ----
  const int lr = l & 15;
  const int g = l >> 4;                            // k-group 0..3
  const int kc0 = (((g * 2) ^ (lr & 7)) << 4);     // chunk 2g swizzled
  const int kc1 = (((g * 2 + 1) ^ (lr & 7)) << 4); // chunk 2g+1 swizzled
  const int arow = (wm * 128 + lr) * 128;          // + mi*2048
  const int brow = 32768 + (wn * 64 + lr) * 128;   // + ni*2048

  f32x4 acc[8][4];
  #pragma unroll
  for (int mi = 0; mi < 8; ++mi)
    #pragma unroll
    for (int ni = 0; ni < 4; ++ni) acc[mi][ni] = (f32x4){0.f, 0.f, 0.f, 0.f};

  // ---- prologue: stage step 0 in pair order, leave pair3 in flight ----
  STAGE_AC(0, 0); STAGE_AC(0, 2);
  STAGE_BC(0, 0); STAGE_BC(0, 2);
  STAGE_BC(0, 1); STAGE_BC(0, 3);
  STAGE_AC(0, 1); STAGE_AC(0, 3);
  WAITVM(2);
  SBAR();

#define LDSFRAG(base)                                                         \
  __builtin_shufflevector(*(const i32x4*)(bufc + (base) + kc0),               \
                          *(const i32x4*)(bufc + (base) + kc1),               \
                          0, 1, 2, 3, 4, 5, 6, 7)

#define MFMA_CLUSTER(q)                                                       \
  do {                                                                        \
    __builtin_amdgcn_sched_barrier(0);                                        \
    __builtin_amdgcn_s_setprio(1);                                            \
    _Pragma("unroll")                                                         \
    for (int i = 0; i < 2; ++i)                                               \
      _Pragma("unroll")                                                       \
      for (int ni = 0; ni < 4; ++ni)                                          \
        acc[2 * (q) + i][ni] =                                                \
            __builtin_amdgcn_mfma_scale_f32_16x16x128_f8f6f4(                 \
                af[i], bf[ni], acc[2 * (q) + i][ni], 0, 0,                    \
                0, 0x7F7F7F7F, 0, 0x7F7F7F7F);                                \
    __builtin_amdgcn_s_setprio(0);                                            \
    __builtin_amdgcn_sched_barrier(0);                                        \
  } while (0)

  #pragma unroll 2
  for (int T = 0; T < NTS; ++T) {
    const u8* bufc = lds + (T & 1) * LDSB;
    const int Tn = T + 1;
    const bool st = (Tn < NTS);
    i32x8 bf[4];
    i32x8 af[2];

    // ---- phase 0: B all (regs for whole step) + A mi0,1; stage (A-c0,A-c2)
    #pragma unroll
    for (int ni = 0; ni < 4; ++ni) bf[ni] = LDSFRAG(brow + ni * 2048);
    af[0] = LDSFRAG(arow);
    af[1] = LDSFRAG(arow + 2048);
    if (st) { STAGE_AC(Tn, 0); STAGE_AC(Tn, 2); }
    SBAR();
    MFMA_CLUSTER(0);
    SBAR();

    // ---- phase 1: A mi2,3; stage (B-c0,B-c2)
    af[0] = LDSFRAG(arow + 4096);
    af[1] = LDSFRAG(arow + 6144);
    if (st) { STAGE_BC(Tn, 0); STAGE_BC(Tn, 2); }
    SBAR();
    MFMA_CLUSTER(1);
    SBAR();

    // ---- phase 2: drain this step's late A-halves; A mi4,5; stage (B-c1,B-c3)
    if (T < NTS - 1) { WAITVM(4); } else { WAITVM(0); }
    af[0] = LDSFRAG(arow + 8192);
    af[1] = LDSFRAG(arow + 10240);
    if (st) { STAGE_BC(Tn, 1); STAGE_BC(Tn, 3); }
    SBAR();
    MFMA_CLUSTER(2);
    SBAR();

    // ---- phase 3: A mi6,7; stage (A-c1,A-c3); boundary wait vmcnt(2)
    af[0] = LDSFRAG(arow + 12288);
    af[1] = LDSFRAG(arow + 14336);
    if (st) { STAGE_AC(Tn, 1); STAGE_AC(Tn, 3); }
    SBAR();
    MFMA_CLUSTER(3);
    WAITVM(2);  // pairs 0,1,2 of step T+1 landed; pair3 may fly
    SBAR();
  }

  // ---- epilogue: exp-sum over 8 slot-columns per class ----
  const int rbase = n0 + wm * 128 + ((l >> 4) * 4);
  #pragma unroll
  for (int mi = 0; mi < 8; ++mi) {
    #pragma unroll
    for (int ni = 0; ni < 4; ++ni) {
      const int colbase = r0 + wn * 64 + ni * 16 + (l & 15);
      const int cls = colbase >> 3;
      #pragma unroll
      for (int rg = 0; rg < 4; ++rg) {
        float e = __expf(acc[mi][ni][rg] - 1.0f);
        e += __shfl_xor(e, 1);
        e += __shfl_xor(e, 2);
        e += __shfl_xor(e, 4);
        if ((l & 7) == 0 && cls < KK) {
          out[(size_t)(rbase + mi * 16 + rg) * KK + cls] = -fminf(e, 3.0e38f);
        }
      }
    }
  }
}

extern "C" void kernel_launch(void* const* d_in, const int* in_sizes, int n_in,
                              void* d_out, int out_size, void* d_ws, size_t ws_size,
                              hipStream_t stream) {
  const float* x    = (const float*)d_in[0];
  const float* tl   = (const float*)d_in[1];
  const float* mem  = (const float*)d_in[2];
  const float* ment = (const float*)d_in[3];
  float* out = (float*)d_out;

  char* ws = (char*)d_ws;
  int2* cand = (int2*)ws;                      // 64 KB
  int*  sel  = (int*)(ws + NN * 8);            // 32 KB
  u8*   Bq   = (u8*)(ws + (1 << 20));                    // RRP*DD = 8.4 MB
  u8*   xq   = (u8*)(ws + (1 << 20) + (size_t)RRP * DD); // NN*DD = 8.4 MB

  hipLaunchKernelGGL(stats_kernel, dim3(NN), dim3(256), 0, stream, tl, cand);
  hipLaunchKernelGGL(select_kernel, dim3(250), dim3(256), 0, stream, cand, ment, sel);
  hipLaunchKernelGGL(convgather_kernel, dim3(NN + RRP), dim3(128), 0, stream,
                     x, mem, sel, xq, Bq);
  hipLaunchKernelGGL(logits_kernel, dim3(32, 32), dim3(512), 0, stream, xq, Bq, out);
}

// Round 12
// 224.060 us; speedup vs baseline: 1.7827x; 1.7827x over previous
//
#include <hip/hip_runtime.h>
#include <hip/hip_bf16.h>
#include <math.h>

#define NN 8192
#define KK 1000
#define SS 8
#define DD 1024
#define RR (KK * SS)   // 8000 memory rows
#define RRP 8192       // padded to 32 * 256

typedef __bf16 bf16x8 __attribute__((ext_vector_type(8)));
typedef float f32x4 __attribute__((ext_vector_type(4)));
typedef unsigned short ushort_t;
typedef ushort_t ushort8 __attribute__((ext_vector_type(8)));

static __device__ __forceinline__ ushort_t f2bf(float f) {
  unsigned u = __float_as_uint(f);
  unsigned r = (u + 0x7FFFu + ((u >> 16) & 1u)) >> 16;  // round-nearest-even
  return (ushort_t)r;
}

// direct global->LDS DMA, 16 B per lane; LDS dest = wave-uniform base + lane*16
#define GLD16(gsrc, ldst)                                                     \
  __builtin_amdgcn_global_load_lds(                                           \
      (const __attribute__((address_space(1))) unsigned int*)(gsrc),          \
      (__attribute__((address_space(3))) unsigned int*)(ldst), 16, 0, 0)

#define SBAR() asm volatile("s_barrier" ::: "memory")
#define WAITVM(n) asm volatile("s_waitcnt vmcnt(" #n ")" ::: "memory")

// ---------------------------------------------------------------------------
// Kernel A: per-sample softmax stats, one WAVE per row, row in registers.
// Row = 250 float4; lane l holds float4 at cols c*256 + l*4, c=0..3 (guarded:
// only base<=996 valid; 1000%4==0 so no straddle). Three register passes:
// max+first-argmax, Z, entropy. Cross-lane via 6-step shfl_xor.
// Same math as rounds 2-10 (expf/logf, first-occurrence argmax, plab=1/Z).
// ---------------------------------------------------------------------------
__global__ __launch_bounds__(256) void stats_kernel(
    const float* __restrict__ tl, int2* __restrict__ cand) {
  const int wid = (blockIdx.x * 256 + threadIdx.x) >> 6;  // row
  const int l = threadIdx.x & 63;
  if (wid >= NN) return;
  const float* row = tl + (size_t)wid * KK;

  float vf[16];
  bool vld[4];
  #pragma unroll
  for (int c = 0; c < 4; ++c) {
    const int base = c * 256 + l * 4;
    vld[c] = (base <= KK - 4);
    if (vld[c]) {
      const float4 v = *(const float4*)(row + base);
      vf[c * 4 + 0] = v.x; vf[c * 4 + 1] = v.y;
      vf[c * 4 + 2] = v.z; vf[c * 4 + 3] = v.w;
    } else {
      vf[c * 4 + 0] = vf[c * 4 + 1] = vf[c * 4 + 2] = vf[c * 4 + 3] = -INFINITY;
    }
  }

  // pass 1: max + first-occurrence argmax (per-lane idx ascending, strict >)
  float m = -INFINITY; int bi = 1 << 30;
  #pragma unroll
  for (int c = 0; c < 4; ++c)
    #pragma unroll
    for (int j = 0; j < 4; ++j) {
      const float val = vf[c * 4 + j];
      if (val > m) { m = val; bi = c * 256 + l * 4 + j; }
    }
  #pragma unroll
  for (int off = 32; off > 0; off >>= 1) {
    const float om = __shfl_xor(m, off);
    const int ob = __shfl_xor(bi, off);
    if (om > m || (om == m && ob < bi)) { m = om; bi = ob; }
  }

  // pass 2: Z
  float z = 0.f;
  #pragma unroll
  for (int c = 0; c < 4; ++c)
    if (vld[c])
      #pragma unroll
      for (int j = 0; j < 4; ++j) z += expf(vf[c * 4 + j] - m);
  #pragma unroll
  for (int off = 32; off > 0; off >>= 1) z += __shfl_xor(z, off);

  // pass 3: entropy
  float h = 0.f;
  #pragma unroll
  for (int c = 0; c < 4; ++c)
    if (vld[c])
      #pragma unroll
      for (int j = 0; j < 4; ++j) {
        const float p = expf(vf[c * 4 + j] - m) / z;
        h -= p * logf(p + 1e-6f);
      }
  #pragma unroll
  for (int off = 32; off > 0; off >>= 1) h += __shfl_xor(h, off);

  if (l == 0) {
    const float plab = 1.0f / z;
    const bool c = (plab > 0.03f) && (h > 0.2f) && (h < 0.5f);
    cand[wid] = make_int2(c ? bi : -1, __float_as_int(h));
  }
}

// ---------------------------------------------------------------------------
// Kernel B: per-class sequential eviction, wave-parallel scan.
// ---------------------------------------------------------------------------
__global__ __launch_bounds__(256) void select_kernel(
    const int2* __restrict__ cand, const float* __restrict__ ment,
    int* __restrict__ sel) {
  const int w = threadIdx.x >> 6;
  const int l = threadIdx.x & 63;
  const int k = blockIdx.x * 4 + w;
  if (k >= KK) return;

  float ent[SS]; int idx[SS];
  #pragma unroll
  for (int s = 0; s < SS; ++s) { ent[s] = ment[k * SS + s]; idx[s] = -1; }

  for (int base = 0; base < NN; base += 64) {
    const int2 c = cand[base + l];
    unsigned long long msk = __ballot(c.x == k);
    while (msk) {
      const int src = __ffsll((long long)msk) - 1;
      msk &= msk - 1;
      const float H = __shfl(__int_as_float(c.y), src);
      float mx = ent[0]; int mi = 0;
      #pragma unroll
      for (int s = 1; s < SS; ++s) if (ent[s] > mx) { mx = ent[s]; mi = s; }
      if (H < mx) { ent[mi] = H; idx[mi] = base + src; }
    }
  }
  if (l == 0) {
    #pragma unroll
    for (int s = 0; s < SS; ++s) sel[k * SS + s] = idx[s];
  }
}

// ---------------------------------------------------------------------------
// Kernel B2: fused convert+gather.
// r < NN:  xb[r]  = bf16(x[r])
// r >= NN: Bb[r-NN] = bf16(final memory row r-NN)  (sel>=0 -> x row, pad->0)
// ---------------------------------------------------------------------------
__global__ __launch_bounds__(128) void convgather_kernel(
    const float* __restrict__ x, const float* __restrict__ mem,
    const int* __restrict__ sel, ushort_t* __restrict__ xb,
    ushort_t* __restrict__ Bb) {
  const int r = blockIdx.x;
  const int t = threadIdx.x;
  const float* src;
  ushort_t* dst;
  if (r < NN) {
    src = x + (size_t)r * DD;
    dst = xb + (size_t)r * DD;
  } else {
    const int rr = r - NN;
    dst = Bb + (size_t)rr * DD;
    if (rr >= RR) {
      *(ushort8*)(dst + t * 8) = (ushort8)0;
      return;
    }
    const int sl = sel[rr];
    src = (sl >= 0) ? (x + (size_t)sl * DD) : (mem + (size_t)rr * DD);
  }
  const float4 a = *(const float4*)(src + t * 8);
  const float4 b = *(const float4*)(src + t * 8 + 4);
  ushort8 o;
  o[0] = f2bf(a.x); o[1] = f2bf(a.y); o[2] = f2bf(a.z); o[3] = f2bf(a.w);
  o[4] = f2bf(b.x); o[5] = f2bf(b.y); o[6] = f2bf(b.z); o[7] = f2bf(b.w);
  *(ushort8*)(dst + t * 8) = o;
}

// ---------------------------------------------------------------------------
// Kernel C: bf16 MFMA GEMM + exp-sum epilogue — r10 kernel, unchanged
// (proven 173.5 µs / MfmaUtil 33% / 0 bank conflicts).
// BM=BN=256, BK=64, 8 waves (2M x 4N), 2 LDS buffers (128 KB), 4 phases/step
// with counted vmcnt ledger; chunk-XOR swizzle on 128B rows.
// ---------------------------------------------------------------------------
#define BKS 64
#define NTS (DD / BKS)   // 16 K-steps
#define LDSH 32768       // ushorts per buffer (A 16384 + B 16384)

__global__ __launch_bounds__(512, 2) void logits_kernel(
    const ushort_t* __restrict__ xb, const ushort_t* __restrict__ Bb,
    float* __restrict__ out) {
  __shared__ ushort_t lds[2 * LDSH];  // 128 KB
  const int t = threadIdx.x;
  const int w = t >> 6;    // wave 0..7
  const int l = t & 63;
  const int wm = w >> 2;   // 0..1: M-half (128 rows)
  const int wn = w & 3;    // 0..3: N-quarter (64 cols)
  const int n0 = blockIdx.x * 256;
  const int r0 = blockIdx.y * 256;

  const int srow = w * 8 + (l >> 3);
  const int gcolh = (((l & 7) ^ ((l >> 3) & 7)) << 3);  // halves
  const ushort_t* gA = xb + (size_t)(n0 + srow) * DD + gcolh;
  const ushort_t* gB = Bb + (size_t)(r0 + srow) * DD + gcolh;

#define STAGE_AC(T, c)                                                        \
  GLD16(gA + (size_t)(c) * 64 * DD + (size_t)(T) * BKS,                       \
        lds + ((T) & 1) * LDSH + (c) * 4096 + w * 512)
#define STAGE_BC(T, c)                                                        \
  GLD16(gB + (size_t)(c) * 64 * DD + (size_t)(T) * BKS,                       \
        lds + ((T) & 1) * LDSH + 16384 + (c) * 4096 + w * 512)

  const int lr = l & 15;
  const int ch = l >> 4;  // 16B k-chunk within kk-slice, 0..3
  const int kc0 = ((ch ^ (lr & 7)) << 3);        // kk=0: chunk ch
  const int kc1 = (((4 + ch) ^ (lr & 7)) << 3);  // kk=1: chunk 4+ch
  const int arow = (wm * 128 + lr) * 64;         // + mi*1024
  const int brow = 16384 + (wn * 64 + lr) * 64;  // + ni*1024

  f32x4 acc[8][4];
  #pragma unroll
  for (int mi = 0; mi < 8; ++mi)
    #pragma unroll
    for (int ni = 0; ni < 4; ++ni) acc[mi][ni] = (f32x4){0.f, 0.f, 0.f, 0.f};

  // ---- prologue: stage step 0 in pair order, leave pair3 in flight ----
  STAGE_AC(0, 0); STAGE_AC(0, 2);
  STAGE_BC(0, 0); STAGE_BC(0, 2);
  STAGE_BC(0, 1); STAGE_BC(0, 3);
  STAGE_AC(0, 1); STAGE_AC(0, 3);
  WAITVM(2);
  SBAR();

#define MFMA_CLUSTER(q)                                                       \
  do {                                                                        \
    __builtin_amdgcn_sched_barrier(0);                                        \
    __builtin_amdgcn_s_setprio(1);                                            \
    _Pragma("unroll")                                                         \
    for (int i = 0; i < 2; ++i)                                               \
      _Pragma("unroll")                                                       \
      for (int ni = 0; ni < 4; ++ni)                                          \
        acc[2 * (q) + i][ni] = __builtin_amdgcn_mfma_f32_16x16x32_bf16(       \
            af[i][0], bf[ni][0], acc[2 * (q) + i][ni], 0, 0, 0);              \
    _Pragma("unroll")                                                         \
    for (int i = 0; i < 2; ++i)                                               \
      _Pragma("unroll")                                                       \
      for (int ni = 0; ni < 4; ++ni)                                          \
        acc[2 * (q) + i][ni] = __builtin_amdgcn_mfma_f32_16x16x32_bf16(       \
            af[i][1], bf[ni][1], acc[2 * (q) + i][ni], 0, 0, 0);              \
    __builtin_amdgcn_s_setprio(0);                                            \
    __builtin_amdgcn_sched_barrier(0);                                        \
  } while (0)

  #pragma unroll 2
  for (int T = 0; T < NTS; ++T) {
    const ushort_t* buf = lds + (T & 1) * LDSH;
    const int Tn = T + 1;
    const bool st = (Tn < NTS);
    bf16x8 bf[4][2];
    bf16x8 af[2][2];

    // ---- phase 0: B all (regs for whole step) + A mi0,1; stage (A-c0,A-c2)
    #pragma unroll
    for (int ni = 0; ni < 4; ++ni) {
      bf[ni][0] = *(const bf16x8*)(buf + brow + ni * 1024 + kc0);
      bf[ni][1] = *(const bf16x8*)(buf + brow + ni * 1024 + kc1);
    }
    af[0][0] = *(const bf16x8*)(buf + arow + kc0);
    af[0][1] = *(const bf16x8*)(buf + arow + kc1);
    af[1][0] = *(const bf16x8*)(buf + arow + 1024 + kc0);
    af[1][1] = *(const bf16x8*)(buf + arow + 1024 + kc1);
    if (st) { STAGE_AC(Tn, 0); STAGE_AC(Tn, 2); }
    SBAR();
    MFMA_CLUSTER(0);
    SBAR();

    // ---- phase 1: A mi2,3; stage (B-c0,B-c2)
    af[0][0] = *(const bf16x8*)(buf + arow + 2048 + kc0);
    af[0][1] = *(const bf16x8*)(buf + arow + 2048 + kc1);
    af[1][0] = *(const bf16x8*)(buf + arow + 3072 + kc0);
    af[1][1] = *(const bf16x8*)(buf + arow + 3072 + kc1);
    if (st) { STAGE_BC(Tn, 0); STAGE_BC(Tn, 2); }
    SBAR();
    MFMA_CLUSTER(1);
    SBAR();

    // ---- phase 2: drain this step's late A-halves, A mi4,5; stage (B-c1,B-c3)
    if (T < NTS - 1) { WAITVM(4); } else { WAITVM(0); }
    af[0][0] = *(const bf16x8*)(buf + arow + 4096 + kc0);
    af[0][1] = *(const bf16x8*)(buf + arow + 4096 + kc1);
    af[1][0] = *(const bf16x8*)(buf + arow + 5120 + kc0);
    af[1][1] = *(const bf16x8*)(buf + arow + 5120 + kc1);
    if (st) { STAGE_BC(Tn, 1); STAGE_BC(Tn, 3); }
    SBAR();
    MFMA_CLUSTER(2);
    SBAR();

    // ---- phase 3: A mi6,7; stage (A-c1,A-c3); boundary wait vmcnt(2)
    af[0][0] = *(const bf16x8*)(buf + arow + 6144 + kc0);
    af[0][1] = *(const bf16x8*)(buf + arow + 6144 + kc1);
    af[1][0] = *(const bf16x8*)(buf + arow + 7168 + kc0);
    af[1][1] = *(const bf16x8*)(buf + arow + 7168 + kc1);
    if (st) { STAGE_AC(Tn, 1); STAGE_AC(Tn, 3); }
    SBAR();
    MFMA_CLUSTER(3);
    WAITVM(2);  // pairs 0,1,2 of step T+1 landed; pair3 may fly
    SBAR();
  }

  // ---- epilogue: exp-sum over 8 slot-columns per class ----
  const int rbase = n0 + wm * 128 + ((l >> 4) * 4);
  #pragma unroll
  for (int mi = 0; mi < 8; ++mi) {
    #pragma unroll
    for (int ni = 0; ni < 4; ++ni) {
      const int colbase = r0 + wn * 64 + ni * 16 + (l & 15);
      const int cls = colbase >> 3;
      #pragma unroll
      for (int rg = 0; rg < 4; ++rg) {
        float e = __expf(acc[mi][ni][rg] - 1.0f);
        e += __shfl_xor(e, 1);
        e += __shfl_xor(e, 2);
        e += __shfl_xor(e, 4);
        if ((l & 7) == 0 && cls < KK) {
          out[(size_t)(rbase + mi * 16 + rg) * KK + cls] = -fminf(e, 3.0e38f);
        }
      }
    }
  }
}

extern "C" void kernel_launch(void* const* d_in, const int* in_sizes, int n_in,
                              void* d_out, int out_size, void* d_ws, size_t ws_size,
                              hipStream_t stream) {
  const float* x    = (const float*)d_in[0];
  const float* tl   = (const float*)d_in[1];
  const float* mem  = (const float*)d_in[2];
  const float* ment = (const float*)d_in[3];
  float* out = (float*)d_out;

  char* ws = (char*)d_ws;
  int2*     cand = (int2*)ws;                      // 64 KB
  int*      sel  = (int*)(ws + NN * 8);            // 32 KB
  ushort_t* Bb   = (ushort_t*)(ws + (1 << 20));                        // RRP*DD*2 = 16.78 MB
  ushort_t* xb   = (ushort_t*)(ws + (1 << 20) + (size_t)RRP * DD * 2); // NN*DD*2 = 16.78 MB

  hipLaunchKernelGGL(stats_kernel, dim3(NN / 4), dim3(256), 0, stream, tl, cand);
  hipLaunchKernelGGL(select_kernel, dim3(250), dim3(256), 0, stream, cand, ment, sel);
  hipLaunchKernelGGL(convgather_kernel, dim3(NN + RRP), dim3(128), 0, stream,
                     x, mem, sel, xb, Bb);
  hipLaunchKernelGGL(logits_kernel, dim3(32, 32), dim3(512), 0, stream, xb, Bb, out);
}